// Round 3
// baseline (17.014 us; speedup 1.0000x reference)
//
#include <hip/hip_runtime.h>

// LocalPlanarGuidance: x [B=16, C=4, H=96, W=128] fp32, r=8
// out[b, hh, ww] = x[b,3,h,w] / (x[b,0,h,w]*u + x[b,1,h,w]*v + x[b,2,h,w])
// h=hh/8, w=ww/8, u=((ww%8)-3.5)/8, v=((hh%8)-3.5)/8
// Output [16, 768, 1024] fp32.
//
// R3: grid-stride persistent form. 2048 blocks x 256 = 8192 waves =
// exactly 32 waves/CU (full occupancy), 6 float4-quads per thread.
// Cuts workgroup count 6x (amortizes dispatch/tail), keeps stores
// perfectly coalesced (1KB/wave per store instruction).

#define LPG_B 16
#define LPG_H 96
#define LPG_W 128
#define LPG_HOUT 768
#define LPG_WOUT 1024
#define PLANE (LPG_H * LPG_W)      // 12288

#define TOTAL_QUADS (LPG_B * LPG_HOUT * (LPG_WOUT / 4))  // 3,145,728
#define GRID_BLOCKS 2048
#define BLOCK_THREADS 256
#define STRIDE (GRID_BLOCKS * BLOCK_THREADS)             // 524,288 -> 6 iters

__global__ __launch_bounds__(BLOCK_THREADS) void lpg_kernel(const float* __restrict__ x,
                                                            float* __restrict__ out) {
    const int t0 = blockIdx.x * BLOCK_THREADS + threadIdx.x;

#pragma unroll
    for (int it = 0; it < TOTAL_QUADS / STRIDE; ++it) {
        const int t = t0 + it * STRIDE;

        const int wq = t & 255;              // quad index within row (WOUT/4 = 256)
        const int rest = t >> 8;             // b*HOUT + hh
        const int hh = rest % LPG_HOUT;      // magic-mul division
        const int b = rest / LPG_HOUT;

        const int w = wq >> 1;               // input column (two quads per input col)
        const int jbase = (wq & 1) << 2;     // 0 or 4: which half of the 8-wide cell
        const int h = hh >> 3;
        const float v = ((float)(hh & 7) - 3.5f) * 0.125f;

        const int in_base = ((b * 4) * LPG_H + h) * LPG_W + w;
        const float p0 = x[in_base];               // channel 0 (u coeff)
        const float p1 = x[in_base + PLANE];       // channel 1 (v coeff)
        const float p2 = x[in_base + 2 * PLANE];   // channel 2 (const)
        const float p3 = x[in_base + 3 * PLANE];   // channel 3 (numerator)

        const float base = fmaf(p1, v, p2);

        float o[4];
#pragma unroll
        for (int j = 0; j < 4; ++j) {
            const float u = ((float)(jbase + j) - 3.5f) * 0.125f;
            const float denom = fmaf(p0, u, base);
            o[j] = p3 * __builtin_amdgcn_rcpf(denom);
        }

        float4* dst = reinterpret_cast<float4*>(out + ((size_t)t << 2));
        *dst = make_float4(o[0], o[1], o[2], o[3]);
    }
}

extern "C" void kernel_launch(void* const* d_in, const int* in_sizes, int n_in,
                              void* d_out, int out_size, void* d_ws, size_t ws_size,
                              hipStream_t stream) {
    (void)in_sizes; (void)n_in; (void)d_ws; (void)ws_size; (void)out_size;
    const float* x = (const float*)d_in[0];
    float* out = (float*)d_out;
    lpg_kernel<<<GRID_BLOCKS, BLOCK_THREADS, 0, stream>>>(x, out);
}

// Round 4
// 14.003 us; speedup vs baseline: 1.2150x; 1.2150x over previous
//
#include <hip/hip_runtime.h>

// LocalPlanarGuidance: x [B=16, C=4, H=96, W=128] fp32, r=8
// out[b, hh, ww] = x[b,3,h,w] / (x[b,0,h,w]*u + x[b,1,h,w]*v + x[b,2,h,w])
// h=hh/8, w=ww/8, u=((ww%8)-3.5)/8, v=((hh%8)-3.5)/8
// Output [16, 768, 1024] fp32.
//
// R4: identical to R3 (2048 blocks x 256, grid-stride 6 iters, coalesced
// float4 stores) but with NONTEMPORAL stores: the 48MB output stream is
// never re-read, and exceeds the 32MB aggregate L2 -> bypass L2 dirty
// allocate/evict on the write path.

#define LPG_B 16
#define LPG_H 96
#define LPG_W 128
#define LPG_HOUT 768
#define LPG_WOUT 1024
#define PLANE (LPG_H * LPG_W)      // 12288

#define TOTAL_QUADS (LPG_B * LPG_HOUT * (LPG_WOUT / 4))  // 3,145,728
#define GRID_BLOCKS 2048
#define BLOCK_THREADS 256
#define STRIDE (GRID_BLOCKS * BLOCK_THREADS)             // 524,288 -> 6 iters

__global__ __launch_bounds__(BLOCK_THREADS) void lpg_kernel(const float* __restrict__ x,
                                                            float* __restrict__ out) {
    const int t0 = blockIdx.x * BLOCK_THREADS + threadIdx.x;

#pragma unroll
    for (int it = 0; it < TOTAL_QUADS / STRIDE; ++it) {
        const int t = t0 + it * STRIDE;

        const int wq = t & 255;              // quad index within row (WOUT/4 = 256)
        const int rest = t >> 8;             // b*HOUT + hh
        const int hh = rest % LPG_HOUT;      // magic-mul division
        const int b = rest / LPG_HOUT;

        const int w = wq >> 1;               // input column (two quads per input col)
        const int jbase = (wq & 1) << 2;     // 0 or 4: which half of the 8-wide cell
        const int h = hh >> 3;
        const float v = ((float)(hh & 7) - 3.5f) * 0.125f;

        const int in_base = ((b * 4) * LPG_H + h) * LPG_W + w;
        const float p0 = x[in_base];               // channel 0 (u coeff)
        const float p1 = x[in_base + PLANE];       // channel 1 (v coeff)
        const float p2 = x[in_base + 2 * PLANE];   // channel 2 (const)
        const float p3 = x[in_base + 3 * PLANE];   // channel 3 (numerator)

        const float base = fmaf(p1, v, p2);

        float o[4];
#pragma unroll
        for (int j = 0; j < 4; ++j) {
            const float u = ((float)(jbase + j) - 3.5f) * 0.125f;
            const float denom = fmaf(p0, u, base);
            o[j] = p3 * __builtin_amdgcn_rcpf(denom);
        }

        float* dst = out + ((size_t)t << 2);
        __builtin_nontemporal_store(o[0], dst + 0);
        __builtin_nontemporal_store(o[1], dst + 1);
        __builtin_nontemporal_store(o[2], dst + 2);
        __builtin_nontemporal_store(o[3], dst + 3);
    }
}

extern "C" void kernel_launch(void* const* d_in, const int* in_sizes, int n_in,
                              void* d_out, int out_size, void* d_ws, size_t ws_size,
                              hipStream_t stream) {
    (void)in_sizes; (void)n_in; (void)d_ws; (void)ws_size; (void)out_size;
    const float* x = (const float*)d_in[0];
    float* out = (float*)d_out;
    lpg_kernel<<<GRID_BLOCKS, BLOCK_THREADS, 0, stream>>>(x, out);
}